// Round 1
// baseline (7561.457 us; speedup 1.0000x reference)
//
#include <hip/hip_runtime.h>
#include <math.h>

#define B_   16
#define T_   24
#define H_   96
#define W_   96
#define CIN_ 16
#define CF_  16
#define CG_  64   // 4*CF (gates i,f,c,o)

#define TY_  16
#define TX_  16

__device__ __forceinline__ float sigmoidf_(float x) {
    return 1.0f / (1.0f + expf(-x));
}

__global__ __launch_bounds__(256) void convlstm_step(
    const float* __restrict__ inputs,   // (B,T,H,W,CIN)
    const float* __restrict__ Wk,       // (3,3,CIN,64)
    const float* __restrict__ Uk,       // (3,3,CF,64)
    const float* __restrict__ bias,     // (64)
    const float* __restrict__ h_prev,   // (B,H,W,CF)
    const float* __restrict__ c_prev,   // (B,H,W,CF)
    float* __restrict__ h_new,          // (B,H,W,CF)
    float* __restrict__ c_new,          // (B,H,W,CF) (may alias c_prev)
    const float* __restrict__ dense_w,  // (16)
    const float* __restrict__ dense_b,  // (1)
    float* __restrict__ out,            // (B,H,W) or nullptr
    int t)
{
    const int b    = blockIdx.y;
    const int tile = blockIdx.x;              // 0..35
    const int ty0  = (tile / (W_ / TX_)) * TY_;
    const int tx0  = (tile % (W_ / TX_)) * TX_;
    const int ty   = threadIdx.x >> 4;
    const int tx   = threadIdx.x & 15;
    const int y    = ty0 + ty;
    const int x    = tx0 + tx;

    const float* xb = inputs + (size_t)(b * T_ + t) * (H_ * W_ * CIN_);
    const float* hb = h_prev + (size_t)b * (H_ * W_ * CF_);

    float acc[CG_];
    #pragma unroll
    for (int o = 0; o < CG_; ++o) acc[o] = bias[o];

    // 9 taps as a runtime loop (keeps code ~16KB, fits I$)
    for (int tap = 0; tap < 9; ++tap) {
        const int dy = tap / 3 - 1;
        const int dx = tap % 3 - 1;
        const int yy = y + dy;
        const int xi = x + dx;
        const bool ok = ((unsigned)yy < (unsigned)H_) && ((unsigned)xi < (unsigned)W_);
        const float* wp = Wk + tap * (CIN_ * CG_);   // wave-uniform
        const float* up = Uk + tap * (CF_ * CG_);    // wave-uniform
        const size_t voff = ((size_t)yy * W_ + xi) * CIN_;
        const float4* xv4 = (const float4*)(xb + voff);
        const float4* hv4 = (const float4*)(hb + voff);

        #pragma unroll
        for (int c4 = 0; c4 < 4; ++c4) {
            float4 xv = ok ? xv4[c4] : make_float4(0.f, 0.f, 0.f, 0.f);
            float4 hv = ok ? hv4[c4] : make_float4(0.f, 0.f, 0.f, 0.f);
            const float xs[4] = {xv.x, xv.y, xv.z, xv.w};
            const float hs[4] = {hv.x, hv.y, hv.z, hv.w};
            #pragma unroll
            for (int j = 0; j < 4; ++j) {
                const int cin = c4 * 4 + j;
                const float* wrow = wp + cin * CG_;
                const float* urow = up + cin * CG_;
                #pragma unroll
                for (int o = 0; o < CG_; ++o) {
                    acc[o] = fmaf(xs[j], wrow[o], acc[o]);
                    acc[o] = fmaf(hs[j], urow[o], acc[o]);
                }
            }
        }
    }

    // Gate math + state update (Keras order i,f,c,o)
    const size_t pbase = (size_t)b * (H_ * W_) + (size_t)y * W_ + x;
    const size_t p16   = pbase * CF_;
    const float4* cp4 = (const float4*)(c_prev + p16);
    float4*       cn4 = (float4*)(c_new + p16);
    float4*       hn4 = (float4*)(h_new + p16);

    float dsum = 0.0f;
    #pragma unroll
    for (int q = 0; q < 4; ++q) {
        float4 cp = cp4[q];
        const float cpv[4] = {cp.x, cp.y, cp.z, cp.w};
        float cnv[4], hnv[4];
        #pragma unroll
        for (int j = 0; j < 4; ++j) {
            const int k = q * 4 + j;
            float ig = sigmoidf_(acc[k]);
            float fg = sigmoidf_(acc[16 + k]);
            float gg = fmaxf(acc[32 + k], 0.0f);
            float og = sigmoidf_(acc[48 + k]);
            float cn = fg * cpv[j] + ig * gg;
            float hn = og * fmaxf(cn, 0.0f);
            cnv[j] = cn;
            hnv[j] = hn;
            dsum = fmaf(hn, dense_w[k], dsum);
        }
        cn4[q] = make_float4(cnv[0], cnv[1], cnv[2], cnv[3]);
        hn4[q] = make_float4(hnv[0], hnv[1], hnv[2], hnv[3]);
    }

    if (out) {
        out[pbase] = dsum + dense_b[0];
    }
}

extern "C" void kernel_launch(void* const* d_in, const int* in_sizes, int n_in,
                              void* d_out, int out_size, void* d_ws, size_t ws_size,
                              hipStream_t stream) {
    const float* inputs = (const float*)d_in[0];
    const float* Wk     = (const float*)d_in[1];
    const float* Uk     = (const float*)d_in[2];
    const float* bias   = (const float*)d_in[3];
    const float* dw     = (const float*)d_in[4];
    const float* db     = (const float*)d_in[5];
    float* out = (float*)d_out;

    const size_t hc = (size_t)B_ * H_ * W_ * CF_;   // 2 359 296 floats
    float* h0 = (float*)d_ws;
    float* h1 = h0 + hc;
    float* cc = h1 + hc;

    // ws is poisoned to 0xAA before every launch — zero the initial state.
    hipMemsetAsync(h0, 0, hc * sizeof(float), stream);
    hipMemsetAsync(cc, 0, hc * sizeof(float), stream);

    dim3 grid((H_ / TY_) * (W_ / TX_), B_);   // (36, 16)
    for (int t = 0; t < T_; ++t) {
        const float* hp = (t & 1) ? h1 : h0;
        float*       hn = (t & 1) ? h0 : h1;
        convlstm_step<<<grid, 256, 0, stream>>>(
            inputs, Wk, Uk, bias, hp, cc, hn, cc, dw, db,
            (t == T_ - 1) ? out : (float*)nullptr, t);
    }
}

// Round 2
// 2344.285 us; speedup vs baseline: 3.2255x; 3.2255x over previous
//
#include <hip/hip_runtime.h>
#include <math.h>

#define B_   16
#define T_   24
#define H_   96
#define W_   96
#define HW_  (H_ * W_)
#define CIN_ 16
#define CF_  16

__device__ __forceinline__ float sigmoidf_(float x) {
    return 1.0f / (1.0f + expf(-x));
}

// Pack weights per filter-group fg (4 filters x 4 gates = 16 channels), so a
// wave handling fg reads 16 contiguous floats (64B) per (tap,cin) -> s_load_dwordx16.
// Layout: Wp[fg][tap][cin][g*4+j]  where global channel = g*16 + fg*4 + j.
__global__ void pack_weights(const float* __restrict__ Wk,
                             const float* __restrict__ Uk,
                             const float* __restrict__ bias,
                             float* __restrict__ Wp, float* __restrict__ Up,
                             float* __restrict__ bp) {
    int i = blockIdx.x * 256 + threadIdx.x;
    const int N = 4 * 9 * 16 * 16;  // 9216
    if (i < N) {
        int o16 = i & 15;            // g*4 + j
        int cin = (i >> 4) & 15;
        int tap = (i >> 8) % 9;
        int fg  = i / (9 * 16 * 16);
        int g = o16 >> 2, j = o16 & 3;
        int src = (tap * CIN_ + cin) * 64 + g * 16 + fg * 4 + j;
        Wp[i] = Wk[src];
        Up[i] = Uk[src];
    }
    if (i < 64) {
        int o16 = i & 15; int fg = i >> 4;
        int g = o16 >> 2, j = o16 & 3;
        bp[i] = bias[g * 16 + fg * 4 + j];
    }
}

// One wave = one filter-group (fg uniform per wave), 64 consecutive points.
// Block = 256 threads = 4 waves = all 4 fg groups for the same 64 points.
// State is planar: h,c stored as [B][4(fg)][HW][4] floats (float4 per point/plane).
__global__ __launch_bounds__(256) void convlstm_step(
    const float* __restrict__ inputs,   // (B,T,H,W,16)
    const float* __restrict__ Wp,       // [4][9][16][16]
    const float* __restrict__ Up,       // [4][9][16][16]
    const float* __restrict__ bp,       // [4][16]
    const float* __restrict__ h_prev,   // planar
    float* __restrict__ h_new,          // planar
    float* __restrict__ c_state,        // planar, updated in place
    int t)
{
    const int b    = blockIdx.y;
    const int lane = threadIdx.x & 63;
    const int fg   = __builtin_amdgcn_readfirstlane(threadIdx.x >> 6);
    const int p    = blockIdx.x * 64 + lane;       // 0..9215
    const int y    = p / W_;
    const int x    = p - y * W_;

    const float* xb = inputs + ((size_t)(b * T_ + t)) * (HW_ * CIN_);
    const float* hb = h_prev + (size_t)b * (4 * HW_ * 4);
    const float* wf = Wp + fg * (9 * 16 * 16);
    const float* uf = Up + fg * (9 * 16 * 16);
    const float* bf = bp + fg * 16;

    float acc[16];
    #pragma unroll
    for (int o = 0; o < 16; ++o) acc[o] = bf[o];

    for (int tap = 0; tap < 9; ++tap) {
        const int dy = tap / 3 - 1;
        const int dx = tap % 3 - 1;
        const int yy = y + dy;
        const int xi = x + dx;
        const bool ok = ((unsigned)yy < (unsigned)H_) && ((unsigned)xi < (unsigned)W_);
        const int np = yy * W_ + xi;

        float4 xv[4], hv[4];
        #pragma unroll
        for (int c4 = 0; c4 < 4; ++c4) {
            xv[c4] = ok ? *(const float4*)(xb + (size_t)np * CIN_ + c4 * 4)
                        : make_float4(0.f, 0.f, 0.f, 0.f);
            // h plane c4 (cin group == fg plane of h), element np
            hv[c4] = ok ? *(const float4*)(hb + ((size_t)c4 * HW_ + np) * 4)
                        : make_float4(0.f, 0.f, 0.f, 0.f);
        }

        const float* wt = wf + tap * 256;   // [cin][16], contiguous 64B rows
        const float* ut = uf + tap * 256;

        #pragma unroll
        for (int c4 = 0; c4 < 4; ++c4) {
            const float xs[4] = {xv[c4].x, xv[c4].y, xv[c4].z, xv[c4].w};
            const float hs[4] = {hv[c4].x, hv[c4].y, hv[c4].z, hv[c4].w};
            #pragma unroll
            for (int j = 0; j < 4; ++j) {
                const int cin = c4 * 4 + j;
                const float* wrow = wt + cin * 16;  // wave-uniform addr -> s_load
                const float* urow = ut + cin * 16;
                #pragma unroll
                for (int o = 0; o < 16; ++o) {
                    acc[o] = fmaf(xs[j], wrow[o], acc[o]);
                    acc[o] = fmaf(hs[j], urow[o], acc[o]);
                }
            }
        }
    }

    // acc[g*4+j]: g=0 i, g=1 f, g=2 c, g=3 o ; filter k = fg*4+j
    const size_t pb = ((size_t)b * 4 + fg) * HW_ + p;   // float4 element index
    float4* cs = (float4*)c_state + pb;
    float4* hs = (float4*)h_new + pb;
    float4 cp = *cs;
    const float cpv[4] = {cp.x, cp.y, cp.z, cp.w};
    float cnv[4], hnv[4];
    #pragma unroll
    for (int j = 0; j < 4; ++j) {
        float ig = sigmoidf_(acc[j]);
        float fg_ = sigmoidf_(acc[4 + j]);
        float gg = fmaxf(acc[8 + j], 0.0f);
        float og = sigmoidf_(acc[12 + j]);
        float cn = fg_ * cpv[j] + ig * gg;
        float hn = og * fmaxf(cn, 0.0f);
        cnv[j] = cn;
        hnv[j] = hn;
    }
    *cs = make_float4(cnv[0], cnv[1], cnv[2], cnv[3]);
    *hs = make_float4(hnv[0], hnv[1], hnv[2], hnv[3]);
}

// Dense(1): out[b,p] = sum_k h[b, plane k/4, p, k%4] * dw[k] + db
__global__ __launch_bounds__(256) void dense_out(
    const float* __restrict__ h,        // planar [B][4][HW][4]
    const float* __restrict__ dw,       // (16)
    const float* __restrict__ db,       // (1)
    float* __restrict__ out)            // (B*HW)
{
    int i = blockIdx.x * 256 + threadIdx.x;   // 0 .. B*HW-1
    int b = i / HW_;
    int p = i - b * HW_;
    float s = db[0];
    #pragma unroll
    for (int fg = 0; fg < 4; ++fg) {
        float4 hv = ((const float4*)h)[((size_t)b * 4 + fg) * HW_ + p];
        s = fmaf(hv.x, dw[fg * 4 + 0], s);
        s = fmaf(hv.y, dw[fg * 4 + 1], s);
        s = fmaf(hv.z, dw[fg * 4 + 2], s);
        s = fmaf(hv.w, dw[fg * 4 + 3], s);
    }
    out[i] = s;
}

extern "C" void kernel_launch(void* const* d_in, const int* in_sizes, int n_in,
                              void* d_out, int out_size, void* d_ws, size_t ws_size,
                              hipStream_t stream) {
    const float* inputs = (const float*)d_in[0];
    const float* Wk     = (const float*)d_in[1];
    const float* Uk     = (const float*)d_in[2];
    const float* bias   = (const float*)d_in[3];
    const float* dw     = (const float*)d_in[4];
    const float* db     = (const float*)d_in[5];
    float* out = (float*)d_out;

    const size_t hc = (size_t)B_ * 4 * HW_ * 4;   // 2,359,296 floats per state
    float* h0 = (float*)d_ws;
    float* h1 = h0 + hc;
    float* cc = h1 + hc;
    float* Wp = cc + hc;
    float* Up = Wp + 4 * 9 * 16 * 16;
    float* bp = Up + 4 * 9 * 16 * 16;

    pack_weights<<<36, 256, 0, stream>>>(Wk, Uk, bias, Wp, Up, bp);

    // ws is poisoned to 0xAA before every launch — zero the initial state.
    hipMemsetAsync(h0, 0, hc * sizeof(float), stream);
    hipMemsetAsync(cc, 0, hc * sizeof(float), stream);

    dim3 grid(HW_ / 64, B_);   // (144, 16)
    for (int t = 0; t < T_; ++t) {
        const float* hp = (t & 1) ? h1 : h0;
        float*       hn = (t & 1) ? h0 : h1;
        convlstm_step<<<grid, 256, 0, stream>>>(
            inputs, Wp, Up, bp, hp, hn, cc, t);
    }

    const float* h_last = (T_ & 1) ? h1 : h0;   // T=24 even -> last write to h1? t=23 odd -> hn=h0
    // t=23: (t&1)=1 -> hn = h0
    dense_out<<<(B_ * HW_) / 256, 256, 0, stream>>>(h0, dw, db, out);
    (void)h_last; (void)ws_size; (void)n_in; (void)in_sizes; (void)out_size;
}

// Round 3
// 866.491 us; speedup vs baseline: 8.7265x; 2.7055x over previous
//
#include <hip/hip_runtime.h>
#include <math.h>

#define B_  16
#define T_  24
#define HH_ 96
#define WW_ 96
#define HW_ (HH_ * WW_)

typedef __attribute__((ext_vector_type(8))) short short8v;  // 8 bf16 = 4 VGPR
typedef __attribute__((ext_vector_type(4))) float f32x4;

__device__ __forceinline__ unsigned short f2bf(float x) {
    union { float f; unsigned u; } v; v.f = x;
    unsigned u = v.u + 0x7FFFu + ((v.u >> 16) & 1u);   // RNE
    return (unsigned short)(u >> 16);
}
__device__ __forceinline__ float bf2f(unsigned short b) {
    union { unsigned u; float f; } v; v.u = ((unsigned)b) << 16; return v.f;
}
__device__ __forceinline__ float sigm(float x) { return 1.0f / (1.0f + expf(-x)); }

// ---------------------------------------------------------------------------
// Pack W (3,3,16,64) and U (3,3,16,64) into MFMA B-fragment order, bf16 hi/lo.
// K ordering: k = tap*32 + src*16 + ch (src: 0=x/W, 1=h/U). For 16x16x32:
// B(k,n): lane = (k%32/8)*16 + (n%16), elem = k%8.  Bp[frag=tap*4+ntile][lane][8]
// ---------------------------------------------------------------------------
__global__ void pack_w(const float* __restrict__ Wk, const float* __restrict__ Uk,
                       unsigned short* __restrict__ Bh, unsigned short* __restrict__ Bl) {
    int i = blockIdx.x * 256 + threadIdx.x;
    if (i >= 288 * 64) return;
    int n   = i & 63;
    int k   = i >> 6;
    int tap = k >> 5;
    int kk  = k & 31;
    int srcsel = kk >> 4;
    int ch  = kk & 15;
    int sec = kk >> 3;          // k-group (0..3)
    int e   = kk & 7;
    int lane = sec * 16 + (n & 15);
    int frag = tap * 4 + (n >> 4);
    int dst  = (frag * 64 + lane) * 8 + e;
    float v = (srcsel ? Uk : Wk)[(tap * 16 + ch) * 64 + n];
    unsigned short hi = f2bf(v);
    Bh[dst] = hi;
    Bl[dst] = f2bf(v - bf2f(hi));
}

// ---------------------------------------------------------------------------
// One ConvLSTM step. Block = 256 thr = 4 waves, covers 2 image rows (M=192).
// Wave w: mrow = w>>1 (row in pair), nhalf = w&1 (32 of 64 gate channels).
// LDS: staged x/h tile, 4 rows x 98 cols x 128B cells
//      cell inner: [src(x/h)][hi/lo][chhalf][8ch] bf16, chunks XOR-swizzled by
//      ((col&7)<<4).  z-phase aliases the same LDS (192*256B, XOR by p&15).
// ---------------------------------------------------------------------------
__global__ __launch_bounds__(256) void convlstm_mfma(
    const float* __restrict__ inputs,       // (B,T,H,W,16) f32
    const unsigned short* __restrict__ Bh,  // packed W hi
    const unsigned short* __restrict__ Bl,  // packed W lo
    const float* __restrict__ bias,         // (64)
    const unsigned short* __restrict__ hprev, // (B,HW,4 chunks of 8 bf16): hi0-7,hi8-15,lo0-7,lo8-15
    unsigned short* __restrict__ hnew,
    float* __restrict__ cstate,             // (B,HW,16) f32
    const float* __restrict__ dw,           // (16)
    const float* __restrict__ db,           // (1)
    float* __restrict__ outp,               // (B*HW) or nullptr
    int t)
{
    __shared__ __align__(16) char lds[4 * 98 * 128];   // 50176 B
    const int tid = threadIdx.x;
    const int b   = blockIdx.y;
    const int y0  = blockIdx.x * 2;

    const float* xframe = inputs + ((size_t)(b * T_ + t)) * (HW_ * 16);

    // ---- stage: x (f32 -> bf16 hi/lo) and h (copy) into swizzled LDS ----
    for (int i = tid; i < 4 * 98; i += 256) {
        int r = i / 98, c = i - r * 98;
        int y = y0 - 1 + r, cx = c - 1;
        char* cell = lds + ((r * 98 + c) << 7);
        unsigned sw = (unsigned)((c & 7) << 4);
        if (((unsigned)y < 96u) && ((unsigned)cx < 96u)) {
            const float* xp = xframe + ((size_t)y * WW_ + cx) * 16;
            unsigned xh[8], xl[8];   // packed bf16 pairs: xh[q] holds ch 2q,2q+1
            #pragma unroll
            for (int q = 0; q < 4; ++q) {
                f32x4 xv = *(const f32x4*)(xp + q * 4);
                #pragma unroll
                for (int j2 = 0; j2 < 2; ++j2) {
                    float a0 = xv[j2 * 2 + 0], a1 = xv[j2 * 2 + 1];
                    unsigned short h0 = f2bf(a0), h1 = f2bf(a1);
                    unsigned short l0 = f2bf(a0 - bf2f(h0)), l1 = f2bf(a1 - bf2f(h1));
                    xh[q * 2 + j2] = (unsigned)h0 | ((unsigned)h1 << 16);
                    xl[q * 2 + j2] = (unsigned)l0 | ((unsigned)l1 << 16);
                }
            }
            // x chunks: 0 = hi ch0-7, 1 = hi ch8-15, 2 = lo ch0-7, 3 = lo ch8-15
            *(uint4*)(cell + (( 0) ^ sw)) = make_uint4(xh[0], xh[1], xh[2], xh[3]);
            *(uint4*)(cell + ((16) ^ sw)) = make_uint4(xh[4], xh[5], xh[6], xh[7]);
            *(uint4*)(cell + ((32) ^ sw)) = make_uint4(xl[0], xl[1], xl[2], xl[3]);
            *(uint4*)(cell + ((48) ^ sw)) = make_uint4(xl[4], xl[5], xl[6], xl[7]);
            // h chunks 4..7 copied as-is (global layout matches)
            const uint4* hp4 = (const uint4*)(hprev + (((size_t)b * HW_ + (size_t)y * WW_ + cx) << 5));
            #pragma unroll
            for (int g = 0; g < 4; ++g)
                *(uint4*)(cell + (((4 + g) * 16) ^ sw)) = hp4[g];
        } else {
            uint4 z4 = make_uint4(0, 0, 0, 0);
            #pragma unroll
            for (int k = 0; k < 8; ++k)
                *(uint4*)(cell + ((k * 16) ^ sw)) = z4;
        }
    }
    __syncthreads();

    // ---- MFMA main loop ----
    const int lane  = tid & 63;
    const int w     = tid >> 6;
    const int nhalf = w & 1;
    const int mrow  = w >> 1;
    const int lm    = lane & 15;       // A row (point within M-tile) / B col
    const int lsec  = lane >> 4;       // k-group
    const int cofs  = (lsec >> 1) * 64 + (lsec & 1) * 16;   // src*64 + chh*16

    f32x4 acc[6][2];
    #pragma unroll
    for (int m = 0; m < 6; ++m) {
        acc[m][0] = (f32x4){0.f, 0.f, 0.f, 0.f};
        acc[m][1] = (f32x4){0.f, 0.f, 0.f, 0.f};
    }

    const short8v* BhV = (const short8v*)Bh;
    const short8v* BlV = (const short8v*)Bl;

    for (int tap = 0; tap < 9; ++tap) {
        const int dy = tap / 3 - 1, dx = tap % 3 - 1;
        const int fi = (tap * 4 + nhalf * 2) * 64 + lane;
        short8v bh0 = BhV[fi], bh1 = BhV[fi + 64];
        short8v bl0 = BlV[fi], bl1 = BlV[fi + 64];
        const int r = mrow + dy + 1;
        #pragma unroll
        for (int m = 0; m < 6; ++m) {
            const int c = 1 + m * 16 + lm + dx;
            const char* cell = lds + ((r * 98 + c) << 7);
            const unsigned sw = (unsigned)((c & 7) << 4);
            short8v ah = *(const short8v*)(cell + ((unsigned)cofs ^ sw));
            short8v al = *(const short8v*)(cell + ((unsigned)(cofs + 32) ^ sw));
            acc[m][0] = __builtin_amdgcn_mfma_f32_16x16x32_bf16(ah, bh0, acc[m][0], 0, 0, 0);
            acc[m][0] = __builtin_amdgcn_mfma_f32_16x16x32_bf16(al, bh0, acc[m][0], 0, 0, 0);
            acc[m][0] = __builtin_amdgcn_mfma_f32_16x16x32_bf16(ah, bl0, acc[m][0], 0, 0, 0);
            acc[m][1] = __builtin_amdgcn_mfma_f32_16x16x32_bf16(ah, bh1, acc[m][1], 0, 0, 0);
            acc[m][1] = __builtin_amdgcn_mfma_f32_16x16x32_bf16(al, bh1, acc[m][1], 0, 0, 0);
            acc[m][1] = __builtin_amdgcn_mfma_f32_16x16x32_bf16(ah, bl1, acc[m][1], 0, 0, 0);
        }
    }
    __syncthreads();   // staging reads done; safe to overwrite LDS with z

    // ---- z transpose through LDS (aliased). z[p][col], chunk XOR by p&15 ----
    {
        const int colb = nhalf * 32;
        #pragma unroll
        for (int m = 0; m < 6; ++m)
            #pragma unroll
            for (int nt = 0; nt < 2; ++nt) {
                const int col = colb + nt * 16 + lm;
                #pragma unroll
                for (int j = 0; j < 4; ++j) {
                    const int p = mrow * 96 + m * 16 + lsec * 4 + j;  // C row = (lane>>4)*4 + j
                    unsigned a = (unsigned)(p * 256)
                               + (unsigned)((((col >> 2) ^ (p & 15)) << 4))
                               + (unsigned)((col & 3) * 4);
                    *(float*)(lds + a) = acc[m][nt][j];
                }
            }
    }
    __syncthreads();

    // ---- pointwise gate math + state update (+ fused Dense at t=23) ----
    if (tid < 192) {
        const int p  = tid;
        const int y  = y0 + (p >= 96 ? 1 : 0);
        const int cx = p - (p >= 96 ? 96 : 0);
        const size_t pt = (size_t)b * HW_ + (size_t)y * WW_ + cx;
        float* cp = cstate + pt * 16;
        float dsum = 0.f;
        unsigned hw_[8], lw_[8];
        #pragma unroll
        for (int q = 0; q < 8; ++q) { hw_[q] = 0u; lw_[q] = 0u; }
        #pragma unroll
        for (int fq = 0; fq < 4; ++fq) {
            const char* zb = lds + p * 256;
            const unsigned px = (unsigned)(p & 15);
            f32x4 zi = *(const f32x4*)(zb + ((( 0 + fq) ^ px) << 4));
            f32x4 zf = *(const f32x4*)(zb + ((( 4 + fq) ^ px) << 4));
            f32x4 zc = *(const f32x4*)(zb + ((( 8 + fq) ^ px) << 4));
            f32x4 zo = *(const f32x4*)(zb + (((12 + fq) ^ px) << 4));
            f32x4 cv = *(const f32x4*)(cp + fq * 4);
            f32x4 cn;
            #pragma unroll
            for (int j = 0; j < 4; ++j) {
                const int f = fq * 4 + j;
                float vi = sigm(zi[j] + bias[f]);
                float vf = sigm(zf[j] + bias[16 + f]);
                float vc = fmaxf(zc[j] + bias[32 + f], 0.f);
                float vo = sigm(zo[j] + bias[48 + f]);
                float cnew = vf * cv[j] + vi * vc;
                float hn = vo * fmaxf(cnew, 0.f);
                cn[j] = cnew;
                dsum = fmaf(hn, dw[f], dsum);
                unsigned short hb = f2bf(hn);
                unsigned short lb = f2bf(hn - bf2f(hb));
                hw_[f >> 1] |= ((unsigned)hb) << ((f & 1) * 16);
                lw_[f >> 1] |= ((unsigned)lb) << ((f & 1) * 16);
            }
            *(f32x4*)(cp + fq * 4) = cn;
        }
        uint4* hp4 = (uint4*)(hnew + (pt << 5));
        hp4[0] = make_uint4(hw_[0], hw_[1], hw_[2], hw_[3]);
        hp4[1] = make_uint4(hw_[4], hw_[5], hw_[6], hw_[7]);
        hp4[2] = make_uint4(lw_[0], lw_[1], lw_[2], lw_[3]);
        hp4[3] = make_uint4(lw_[4], lw_[5], lw_[6], lw_[7]);
        if (outp) outp[pt] = dsum + db[0];
    }
}

extern "C" void kernel_launch(void* const* d_in, const int* in_sizes, int n_in,
                              void* d_out, int out_size, void* d_ws, size_t ws_size,
                              hipStream_t stream) {
    const float* inputs = (const float*)d_in[0];
    const float* Wk     = (const float*)d_in[1];
    const float* Uk     = (const float*)d_in[2];
    const float* bias   = (const float*)d_in[3];
    const float* dw     = (const float*)d_in[4];
    const float* db     = (const float*)d_in[5];

    const size_t hbytes = (size_t)B_ * HW_ * 32 * sizeof(unsigned short);  // 9,437,184
    char* ws = (char*)d_ws;
    unsigned short* h0 = (unsigned short*)ws;
    unsigned short* h1 = (unsigned short*)(ws + hbytes);
    float*          cc = (float*)(ws + 2 * hbytes);
    unsigned short* Bh = (unsigned short*)(ws + 3 * hbytes);
    unsigned short* Bl = Bh + 288 * 64;

    pack_w<<<(288 * 64 + 255) / 256, 256, 0, stream>>>(Wk, Uk, Bh, Bl);
    hipMemsetAsync(h0, 0, hbytes, stream);                 // h init = 0
    hipMemsetAsync(cc, 0, hbytes, stream);                 // c init = 0 (same byte count)

    dim3 grid(HH_ / 2, B_);   // (48, 16)
    for (int t = 0; t < T_; ++t) {
        const unsigned short* hp = (t & 1) ? h1 : h0;
        unsigned short*       hn = (t & 1) ? h0 : h1;
        convlstm_mfma<<<grid, 256, 0, stream>>>(
            inputs, Bh, Bl, bias, hp, hn, cc, dw, db,
            (t == T_ - 1) ? (float*)d_out : (float*)nullptr, t);
    }
    (void)in_sizes; (void)n_in; (void)out_size; (void)ws_size;
}